// Round 11
// baseline (53.629 us; speedup 1.0000x reference)
//
#include <hip/hip_runtime.h>

// RecPolicy: per-row bidirectional GRU (H=2) + obs linear + scalar head.
// x: (B,18) f32 = [obs(4), j(7), jd(7)] ; out: (B,7) f32
//
// R11 = R10 (wave-private LDS slices, zero barriers) + PERSISTENT waves with
// 1-deep register prefetch: grid 2048, each wave owns 4 tiles of 64 rows;
// tile t+1's 5 float4 loads issue right after staging tile t, so HBM streams
// under tile t's ~2650-cycle compute. (R9 probe: compute=34us, HBM=19us,
// measured 53 = sum -> zero overlap; the convoy is the block lifecycle.)

using v2f = __attribute__((ext_vector_type(2))) float;

__device__ __forceinline__ float fexp2(float x) { return __builtin_amdgcn_exp2f(x); }
__device__ __forceinline__ float frcp(float x)  { return __builtin_amdgcn_rcpf(x); }

struct Cell {
    v2f wr0, wr1, ur0, ur1, br;   // r gates, prescaled by -log2(e)
    v2f wz0, wz1, uz0, uz1, bz;   // z gates, prescaled by -log2(e)
    v2f wn0, wn1, bni;            // n input part, prescaled by 2*log2(e)
    v2f un0, un1, bnh;            // n hidden part, prescaled by 2*log2(e)
};

// ---- setup kernel: prescale weights once into d_ws ----
// ws layout (floats): [0..31] up Cell, [64..95] dn Cell,
//                     [128..139] w_obs, [140..141] b_obs,
//                     [142..143] w_out, [144] b_out
__global__ void prep_kernel(
    const float* __restrict__ w_ih_up, const float* __restrict__ w_hh_up,
    const float* __restrict__ b_ih_up, const float* __restrict__ b_hh_up,
    const float* __restrict__ w_obs,   const float* __restrict__ b_obs,
    const float* __restrict__ w_ih_dn, const float* __restrict__ w_hh_dn,
    const float* __restrict__ b_ih_dn, const float* __restrict__ b_hh_dn,
    const float* __restrict__ w_out,   const float* __restrict__ b_out,
    float* __restrict__ ws)
{
    if (threadIdx.x != 0 || blockIdx.x != 0) return;
    const float s1 = -1.4426950408889634f;  // -log2(e)
    const float s2 =  2.8853900817779268f;  // 2*log2(e)
    #pragma unroll
    for (int c = 0; c < 2; ++c) {
        const float* wi = c ? w_ih_dn : w_ih_up;
        const float* wh = c ? w_hh_dn : w_hh_up;
        const float* bi = c ? b_ih_dn : b_ih_up;
        const float* bh = c ? b_hh_dn : b_hh_up;
        float* o = ws + c * 64;
        o[0] = s1*wi[0]; o[1] = s1*wi[2];  o[2] = s1*wi[1]; o[3] = s1*wi[3];
        o[4] = s1*wh[0]; o[5] = s1*wh[2];  o[6] = s1*wh[1]; o[7] = s1*wh[3];
        o[8] = s1*(bi[0]+bh[0]); o[9] = s1*(bi[1]+bh[1]);
        o[10] = s1*wi[4]; o[11] = s1*wi[6]; o[12] = s1*wi[5]; o[13] = s1*wi[7];
        o[14] = s1*wh[4]; o[15] = s1*wh[6]; o[16] = s1*wh[5]; o[17] = s1*wh[7];
        o[18] = s1*(bi[2]+bh[2]); o[19] = s1*(bi[3]+bh[3]);
        o[20] = s2*wi[8]; o[21] = s2*wi[10]; o[22] = s2*wi[9]; o[23] = s2*wi[11];
        o[24] = s2*bi[4]; o[25] = s2*bi[5];
        o[26] = s2*wh[8]; o[27] = s2*wh[10]; o[28] = s2*wh[9]; o[29] = s2*wh[11];
        o[30] = s2*bh[4]; o[31] = s2*bh[5];
    }
    #pragma unroll
    for (int i = 0; i < 12; ++i) ws[128 + i] = w_obs[i];
    ws[140] = b_obs[0]; ws[141] = b_obs[1];
    ws[142] = w_out[0]; ws[143] = w_out[1];
    ws[144] = b_out[0];
}

// paired-rcp GRU cell: 6 exp2 + 3 rcp
__device__ __forceinline__ void gru(const Cell& c, float x0, float x1, v2f& h) {
    v2f gr = c.br + c.wr0 * x0 + c.wr1 * x1 + c.ur0 * h.x + c.ur1 * h.y;
    v2f gz = c.bz + c.wz0 * x0 + c.wz1 * x1 + c.uz0 * h.x + c.uz1 * h.y;
    v2f dr = (v2f){1.0f + fexp2(gr.x), 1.0f + fexp2(gr.y)};
    v2f dz = (v2f){1.0f + fexp2(gz.x), 1.0f + fexp2(gz.y)};
    float invr = frcp(dr.x * dr.y);
    v2f r = invr * (v2f){dr.y, dr.x};
    v2f gi = c.bni + c.wn0 * x0 + c.wn1 * x1;
    v2f gh = c.bnh + c.un0 * h.x + c.un1 * h.y;
    v2f a  = gi + r * gh;
    v2f da = (v2f){1.0f + fexp2(a.x), 1.0f + fexp2(a.y)};
    float m = -2.0f * frcp(da.x * da.y);
    v2f n = (v2f){fmaf(m, da.y, 1.0f), fmaf(m, da.x, 1.0f)};
    float invz = frcp(dz.x * dz.y);
    v2f z = invz * (v2f){dz.y, dz.x};
    h = n + z * (h - n);
}

// full per-row chain from a source row, writing 7 acts
__device__ __forceinline__ void row_chain(
    const Cell& up, const Cell& dn, const float* __restrict__ W,
    const float* row, float acts[7])
{
    v2f h = (v2f){0.0f, 0.0f};
    v2f hu[7];
    #pragma unroll
    for (int k = 0; k < 7; ++k) {
        const int i = 6 - k;
        gru(up, row[4 + i], row[11 + i], h);
        hu[k] = h;
    }
    {
        v2f t = (v2f){W[140], W[141]};
        #pragma unroll
        for (int c = 0; c < 4; ++c)
            t += (v2f){W[128 + c], W[134 + c]} * row[c];
        t += (v2f){W[132], W[138]} * h.x;
        t += (v2f){W[133], W[139]} * h.y;
        h = t;
    }
    const float wo0 = W[142], wo1 = W[143], bo = W[144];
    #pragma unroll
    for (int k = 0; k < 7; ++k) {
        gru(dn, hu[k].x, hu[k].y, h);
        acts[k] = fmaf(wo0, h.x, fmaf(wo1, h.y, bo));
    }
}

__global__ __launch_bounds__(256) void recpolicy_kernel(
    const float* __restrict__ x, const float* __restrict__ W,
    float* __restrict__ out, int n)
{
    __shared__ float lds[4608];            // 4 waves x 1152 floats = 18 KiB
    const int tid  = threadIdx.x;
    const int wid  = tid >> 6;
    const int lane = tid & 63;
    float* wlds = lds + wid * 1152;

    // wave-uniform prescaled weights (constant indices -> s_load)
    const Cell up = *reinterpret_cast<const Cell*>(W);
    const Cell dn = *reinterpret_cast<const Cell*>(W + 64);

    const int NT = n >> 6;                       // full 64-row tiles
    const int NW = gridDim.x << 2;               // total waves
    const int gw = (blockIdx.x << 2) | wid;      // this wave's id

    const float4* xs = reinterpret_cast<const float4*>(x);

    int t = gw;
    if (t < NT) {
        float4 nx0, nx1, nx2, nx3, nx4;
        {   // prologue: load first tile (288 float4 per tile)
            size_t b = (size_t)t * 288;
            nx0 = xs[b + lane];       nx1 = xs[b + 64 + lane];
            nx2 = xs[b + 128 + lane]; nx3 = xs[b + 192 + lane];
            if (lane < 32) nx4 = xs[b + 256 + lane];
        }
        while (true) {
            {   // stage regs -> wave-private LDS slice
                float4* d = reinterpret_cast<float4*>(wlds);
                d[lane] = nx0;       d[lane + 64]  = nx1;
                d[lane + 128] = nx2; d[lane + 192] = nx3;
                if (lane < 32) d[lane + 256] = nx4;
            }
            const int tn = t + NW;
            if (tn < NT) {   // 1-deep prefetch: HBM hides under compute below
                size_t b = (size_t)tn * 288;
                nx0 = xs[b + lane];       nx1 = xs[b + 64 + lane];
                nx2 = xs[b + 128 + lane]; nx3 = xs[b + 192 + lane];
                if (lane < 32) nx4 = xs[b + 256 + lane];
            }

            // compute this lane's row (all 18 floats consumed -> LDS reads
            // complete before the output writes below, wave program order)
            const float* row = wlds + lane * 18;
            float acts[7];
            row_chain(up, dn, W, row, acts);

            // reuse slice for outputs, then coalesced float4 store (112/tile)
            #pragma unroll
            for (int k = 0; k < 7; ++k) wlds[lane * 7 + k] = acts[k];
            {
                const float4* so = reinterpret_cast<const float4*>(wlds);
                float4* dsto = reinterpret_cast<float4*>(out) + (size_t)t * 112;
                dsto[lane] = so[lane];
                if (lane < 48) dsto[lane + 64] = so[lane + 64];
            }

            if (tn >= NT) break;
            t = tn;
        }
    }

    // ---- tail rows (n % 64 != 0; never taken for B = 2^21) ----
    const int tail0 = NT << 6;
    if (gw == 0 && tail0 < n) {
        const int rg = tail0 + lane;
        if (rg < n) {
            float rowl[18];
            #pragma unroll
            for (int i = 0; i < 18; ++i) rowl[i] = x[(size_t)rg * 18 + i];
            float acts[7];
            row_chain(up, dn, W, rowl, acts);
            #pragma unroll
            for (int k = 0; k < 7; ++k) out[(size_t)rg * 7 + k] = acts[k];
        }
    }
}

extern "C" void kernel_launch(void* const* d_in, const int* in_sizes, int n_in,
                              void* d_out, int out_size, void* d_ws, size_t ws_size,
                              hipStream_t stream) {
    const float* x       = (const float*)d_in[0];
    const float* w_ih_up = (const float*)d_in[1];
    const float* w_hh_up = (const float*)d_in[2];
    const float* b_ih_up = (const float*)d_in[3];
    const float* b_hh_up = (const float*)d_in[4];
    const float* w_obs   = (const float*)d_in[5];
    const float* b_obs   = (const float*)d_in[6];
    const float* w_ih_dn = (const float*)d_in[7];
    const float* w_hh_dn = (const float*)d_in[8];
    const float* b_ih_dn = (const float*)d_in[9];
    const float* b_hh_dn = (const float*)d_in[10];
    const float* w_out   = (const float*)d_in[11];
    const float* b_out   = (const float*)d_in[12];
    float* out = (float*)d_out;
    float* ws  = (float*)d_ws;

    prep_kernel<<<1, 64, 0, stream>>>(
        w_ih_up, w_hh_up, b_ih_up, b_hh_up, w_obs, b_obs,
        w_ih_dn, w_hh_dn, b_ih_dn, b_hh_dn, w_out, b_out, ws);

    const int n = in_sizes[0] / 18;   // 2097152
    recpolicy_kernel<<<2048, 256, 0, stream>>>(x, ws, out, n);
}

// Round 12
// 52.094 us; speedup vs baseline: 1.0295x; 1.0295x over previous
//
#include <hip/hip_runtime.h>

// RecPolicy: per-row bidirectional GRU (H=2) + obs linear + scalar head.
// x: (B,18) f32 = [obs(4), j(7), jd(7)] ; out: (B,7) f32
//
// R12 = NO input staging at all: each lane loads its own row directly as
// 9 x float2 (row stride 72B is 8B-aligned; a wave's 64 rows are one
// contiguous 4.6KB region, so L1 serves the lane overlap and HBM traffic
// is identical to the coalesced path). Zero barriers, no vmcnt(0)
// chokepoint between load and use (R11 counters: VGPR=48 proved the
// compiler sank every register-prefetch attempt; VALU-busy = 34us with
// ~19us VALU-idle from the stage waits). Output via wave-private LDS
// slice -> coalesced float4 stores (R10 pattern). Weights prescaled in ws.

using v2f = __attribute__((ext_vector_type(2))) float;

__device__ __forceinline__ float fexp2(float x) { return __builtin_amdgcn_exp2f(x); }
__device__ __forceinline__ float frcp(float x)  { return __builtin_amdgcn_rcpf(x); }

struct Cell {
    v2f wr0, wr1, ur0, ur1, br;   // r gates, prescaled by -log2(e)
    v2f wz0, wz1, uz0, uz1, bz;   // z gates, prescaled by -log2(e)
    v2f wn0, wn1, bni;            // n input part, prescaled by 2*log2(e)
    v2f un0, un1, bnh;            // n hidden part, prescaled by 2*log2(e)
};

// ---- setup kernel: prescale weights once into d_ws ----
// ws layout (floats): [0..31] up Cell, [64..95] dn Cell,
//                     [128..139] w_obs, [140..141] b_obs,
//                     [142..143] w_out, [144] b_out
__global__ void prep_kernel(
    const float* __restrict__ w_ih_up, const float* __restrict__ w_hh_up,
    const float* __restrict__ b_ih_up, const float* __restrict__ b_hh_up,
    const float* __restrict__ w_obs,   const float* __restrict__ b_obs,
    const float* __restrict__ w_ih_dn, const float* __restrict__ w_hh_dn,
    const float* __restrict__ b_ih_dn, const float* __restrict__ b_hh_dn,
    const float* __restrict__ w_out,   const float* __restrict__ b_out,
    float* __restrict__ ws)
{
    if (threadIdx.x != 0 || blockIdx.x != 0) return;
    const float s1 = -1.4426950408889634f;  // -log2(e)
    const float s2 =  2.8853900817779268f;  // 2*log2(e)
    #pragma unroll
    for (int c = 0; c < 2; ++c) {
        const float* wi = c ? w_ih_dn : w_ih_up;
        const float* wh = c ? w_hh_dn : w_hh_up;
        const float* bi = c ? b_ih_dn : b_ih_up;
        const float* bh = c ? b_hh_dn : b_hh_up;
        float* o = ws + c * 64;
        o[0] = s1*wi[0]; o[1] = s1*wi[2];  o[2] = s1*wi[1]; o[3] = s1*wi[3];
        o[4] = s1*wh[0]; o[5] = s1*wh[2];  o[6] = s1*wh[1]; o[7] = s1*wh[3];
        o[8] = s1*(bi[0]+bh[0]); o[9] = s1*(bi[1]+bh[1]);
        o[10] = s1*wi[4]; o[11] = s1*wi[6]; o[12] = s1*wi[5]; o[13] = s1*wi[7];
        o[14] = s1*wh[4]; o[15] = s1*wh[6]; o[16] = s1*wh[5]; o[17] = s1*wh[7];
        o[18] = s1*(bi[2]+bh[2]); o[19] = s1*(bi[3]+bh[3]);
        o[20] = s2*wi[8]; o[21] = s2*wi[10]; o[22] = s2*wi[9]; o[23] = s2*wi[11];
        o[24] = s2*bi[4]; o[25] = s2*bi[5];
        o[26] = s2*wh[8]; o[27] = s2*wh[10]; o[28] = s2*wh[9]; o[29] = s2*wh[11];
        o[30] = s2*bh[4]; o[31] = s2*bh[5];
    }
    #pragma unroll
    for (int i = 0; i < 12; ++i) ws[128 + i] = w_obs[i];
    ws[140] = b_obs[0]; ws[141] = b_obs[1];
    ws[142] = w_out[0]; ws[143] = w_out[1];
    ws[144] = b_out[0];
}

// paired-rcp GRU cell: 6 exp2 + 3 rcp
__device__ __forceinline__ void gru(const Cell& c, float x0, float x1, v2f& h) {
    v2f gr = c.br + c.wr0 * x0 + c.wr1 * x1 + c.ur0 * h.x + c.ur1 * h.y;
    v2f gz = c.bz + c.wz0 * x0 + c.wz1 * x1 + c.uz0 * h.x + c.uz1 * h.y;
    v2f dr = (v2f){1.0f + fexp2(gr.x), 1.0f + fexp2(gr.y)};
    v2f dz = (v2f){1.0f + fexp2(gz.x), 1.0f + fexp2(gz.y)};
    float invr = frcp(dr.x * dr.y);
    v2f r = invr * (v2f){dr.y, dr.x};
    v2f gi = c.bni + c.wn0 * x0 + c.wn1 * x1;
    v2f gh = c.bnh + c.un0 * h.x + c.un1 * h.y;
    v2f a  = gi + r * gh;
    v2f da = (v2f){1.0f + fexp2(a.x), 1.0f + fexp2(a.y)};
    float m = -2.0f * frcp(da.x * da.y);
    v2f n = (v2f){fmaf(m, da.y, 1.0f), fmaf(m, da.x, 1.0f)};
    float invz = frcp(dz.x * dz.y);
    v2f z = invz * (v2f){dz.y, dz.x};
    h = n + z * (h - n);
}

// full per-row chain from an 18-float row (registers), writing 7 acts
__device__ __forceinline__ void row_chain(
    const Cell& up, const Cell& dn, const float* __restrict__ W,
    const float* row, float acts[7])
{
    v2f h = (v2f){0.0f, 0.0f};
    v2f hu[7];
    #pragma unroll
    for (int k = 0; k < 7; ++k) {
        const int i = 6 - k;
        gru(up, row[4 + i], row[11 + i], h);
        hu[k] = h;
    }
    {
        v2f t = (v2f){W[140], W[141]};
        #pragma unroll
        for (int c = 0; c < 4; ++c)
            t += (v2f){W[128 + c], W[134 + c]} * row[c];
        t += (v2f){W[132], W[138]} * h.x;
        t += (v2f){W[133], W[139]} * h.y;
        h = t;
    }
    const float wo0 = W[142], wo1 = W[143], bo = W[144];
    #pragma unroll
    for (int k = 0; k < 7; ++k) {
        gru(dn, hu[k].x, hu[k].y, h);
        acts[k] = fmaf(wo0, h.x, fmaf(wo1, h.y, bo));
    }
}

__global__ __launch_bounds__(256) void recpolicy_kernel(
    const float* __restrict__ x, const float* __restrict__ W,
    float* __restrict__ out, int n)
{
    __shared__ float sout[1792];           // 4 waves x 448 floats = 7 KiB
    const int tid  = threadIdx.x;
    const int wid  = tid >> 6;
    const int lane = tid & 63;
    float* wout = sout + wid * 448;

    // wave-uniform prescaled weights (constant indices -> s_load)
    const Cell up = *reinterpret_cast<const Cell*>(W);
    const Cell dn = *reinterpret_cast<const Cell*>(W + 64);

    const int gw = (blockIdx.x << 2) | wid;      // global wave id
    const int rowbase = gw << 6;                 // this wave's 64 rows

    if (rowbase + 64 <= n) {
        // ---- direct per-lane row load: 9 x float2 (8B-aligned, row*72) ----
        const int row = rowbase + lane;
        const float2* rp = reinterpret_cast<const float2*>(x + (size_t)row * 18);
        float rowv[18];
        #pragma unroll
        for (int i = 0; i < 9; ++i) {
            float2 v = rp[i];
            rowv[2 * i]     = v.x;
            rowv[2 * i + 1] = v.y;
        }

        float acts[7];
        row_chain(up, dn, W, rowv, acts);

        // stage 7 outputs in wave-private slice, store coalesced float4
        #pragma unroll
        for (int k = 0; k < 7; ++k) wout[lane * 7 + k] = acts[k];
        {
            const float4* so = reinterpret_cast<const float4*>(wout);
            float4* dsto = reinterpret_cast<float4*>(out) + (size_t)gw * 112;
            dsto[lane] = so[lane];
            if (lane < 48) dsto[lane + 64] = so[lane + 64];
        }
    } else if (rowbase < n) {
        // ---- tail (never taken for B = 2^21) ----
        const int rg = rowbase + lane;
        if (rg < n) {
            float rowl[18];
            #pragma unroll
            for (int i = 0; i < 18; ++i) rowl[i] = x[(size_t)rg * 18 + i];
            float acts[7];
            row_chain(up, dn, W, rowl, acts);
            #pragma unroll
            for (int k = 0; k < 7; ++k) out[(size_t)rg * 7 + k] = acts[k];
        }
    }
}

extern "C" void kernel_launch(void* const* d_in, const int* in_sizes, int n_in,
                              void* d_out, int out_size, void* d_ws, size_t ws_size,
                              hipStream_t stream) {
    const float* x       = (const float*)d_in[0];
    const float* w_ih_up = (const float*)d_in[1];
    const float* w_hh_up = (const float*)d_in[2];
    const float* b_ih_up = (const float*)d_in[3];
    const float* b_hh_up = (const float*)d_in[4];
    const float* w_obs   = (const float*)d_in[5];
    const float* b_obs   = (const float*)d_in[6];
    const float* w_ih_dn = (const float*)d_in[7];
    const float* w_hh_dn = (const float*)d_in[8];
    const float* b_ih_dn = (const float*)d_in[9];
    const float* b_hh_dn = (const float*)d_in[10];
    const float* w_out   = (const float*)d_in[11];
    const float* b_out   = (const float*)d_in[12];
    float* out = (float*)d_out;
    float* ws  = (float*)d_ws;

    prep_kernel<<<1, 64, 0, stream>>>(
        w_ih_up, w_hh_up, b_ih_up, b_hh_up, w_obs, b_obs,
        w_ih_dn, w_hh_dn, b_ih_dn, b_hh_dn, w_out, b_out, ws);

    const int n = in_sizes[0] / 18;   // 2097152
    const int grid = (n + 255) / 256; // 4 waves/block, 64 rows/wave
    recpolicy_kernel<<<grid, 256, 0, stream>>>(x, ws, out, n);
}